// Round 12
// baseline (794.077 us; speedup 1.0000x reference)
//
#include <hip/hip_runtime.h>
#include <math.h>

#define N_POINTS 524288
#define NLV      16
#define TSZ      524288
#define TMASK    (TSZ - 1)
#define ASTART   5                  // levels >= ASTART: backward via stored coeffs
#define NA       (NLV - ASTART)     // 11
#define NPH      11                 // gather phases: phase0 = levels 0-5, 1..10 = levels 6..15

static_assert(NA == 11, "NA mismatch");

struct Params { int res[NLV]; };

// ============================================================================
// R12: (1) gather: dense levels 0-5 merged into phase 0 (tables ~6.9MB, high
//     reuse) -> 11 phases; 5 fewer x-reloads/transitions. Predict 306->~270us,
//     FETCH 483->~420MB.  (2) k_density split into k_dmlp (MLP, live ~60,
//     waves(6,8)) + k_bwd (genc+backward, live ~80, waves(4,8)); mask passed
//     through ws by overwriting consumed enc rows (no extra ws). (3) k_color
//     unchanged (control). density-side delta read via total - gather.
// ============================================================================

struct Gather {                      // one level's 8 corner texels + fracs
    float2 t0, t1, t2, t3, t4, t5, t6, t7;
    float fx, fy, fz;
};
struct Enc2 { float e0, e1; };
struct EncA { float e0, e1, a0x, a0y, a0z, a1x, a1y, a1z; };
struct L3v  { float lx, ly, lz; };

// runtime-branch issue (wave-uniform branch; arithmetic identical to template)
__device__ __forceinline__ Gather lv_issue_rt(const float2* __restrict__ lt, const int res,
                                              const bool hashed,
                                              const float xn0, const float xn1, const float xn2)
{
#pragma clang fp contract(off)
    Gather g;
    const float rf = (float)(res - 1);
    const float px = xn0 * rf, py = xn1 * rf, pz = xn2 * rf;
    const float bx = floorf(px), by = floorf(py), bz = floorf(pz);
    g.fx = px - bx; g.fy = py - by; g.fz = pz - bz;
    const int r1 = res - 1;
    const int ix = (int)bx, iy = (int)by, iz = (int)bz;
    const int cx0 = min(max(ix, 0), r1),     cx1 = min(max(ix + 1, 0), r1);
    const int cy0 = min(max(iy, 0), r1),     cy1 = min(max(iy + 1, 0), r1);
    const int cz0 = min(max(iz, 0), r1),     cz1 = min(max(iz + 1, 0), r1);
    unsigned i000, i001, i010, i011, i100, i101, i110, i111;
    if (hashed) {
        const unsigned hx0 = (unsigned)cx0, hx1 = (unsigned)cx1;
        const unsigned hy0 = (unsigned)cy0 * 2654435761u, hy1 = (unsigned)cy1 * 2654435761u;
        const unsigned hz0 = (unsigned)cz0 * 805459861u,  hz1 = (unsigned)cz1 * 805459861u;
        const unsigned e00 = hy0 ^ hz0, e01 = hy0 ^ hz1, e10 = hy1 ^ hz0, e11 = hy1 ^ hz1;
        i000 = (hx0 ^ e00) & TMASK; i001 = (hx0 ^ e01) & TMASK;
        i010 = (hx0 ^ e10) & TMASK; i011 = (hx0 ^ e11) & TMASK;
        i100 = (hx1 ^ e00) & TMASK; i101 = (hx1 ^ e01) & TMASK;
        i110 = (hx1 ^ e10) & TMASK; i111 = (hx1 ^ e11) & TMASK;
    } else {
        const int b00 = res * (cy0 + res * cz0), b01 = res * (cy0 + res * cz1);
        const int b10 = res * (cy1 + res * cz0), b11 = res * (cy1 + res * cz1);
        i000 = (unsigned)(cx0 + b00); i001 = (unsigned)(cx0 + b01);
        i010 = (unsigned)(cx0 + b10); i011 = (unsigned)(cx0 + b11);
        i100 = (unsigned)(cx1 + b00); i101 = (unsigned)(cx1 + b01);
        i110 = (unsigned)(cx1 + b10); i111 = (unsigned)(cx1 + b11);
    }
    // corner order c=0..7 (ox=c>>2, oy=(c>>1)&1, oz=c&1)
    g.t0 = lt[i000]; g.t1 = lt[i001]; g.t2 = lt[i010]; g.t3 = lt[i011];
    g.t4 = lt[i100]; g.t5 = lt[i101]; g.t6 = lt[i110]; g.t7 = lt[i111];
    return g;
}

template<bool HASHED>
__device__ __forceinline__ Gather lv_issue(const float2* __restrict__ lt, const int res,
                                           const float xn0, const float xn1, const float xn2)
{
    return lv_issue_rt(lt, res, HASHED, xn0, xn1, xn2);
}

// enc pair only — bit-exact order (separate mul/add, corner order c=0..7)
__device__ __forceinline__ Enc2 lv_enc(const Gather g)
{
#pragma clang fp contract(off)
    const float gx0 = 1.0f - g.fx, gx1 = g.fx;
    const float gy0 = 1.0f - g.fy, gy1 = g.fy;
    const float gz0 = 1.0f - g.fz, gz1 = g.fz;
    const float pxy00 = gx0 * gy0, pxy01 = gx0 * gy1, pxy10 = gx1 * gy0, pxy11 = gx1 * gy1;
    const float w000 = pxy00 * gz0, w001 = pxy00 * gz1, w010 = pxy01 * gz0, w011 = pxy01 * gz1;
    const float w100 = pxy10 * gz0, w101 = pxy10 * gz1, w110 = pxy11 * gz0, w111 = pxy11 * gz1;
    float e0 = 0.0f, e1 = 0.0f;
    e0 = e0 + w000 * g.t0.x; e1 = e1 + w000 * g.t0.y;
    e0 = e0 + w001 * g.t1.x; e1 = e1 + w001 * g.t1.y;
    e0 = e0 + w010 * g.t2.x; e1 = e1 + w010 * g.t2.y;
    e0 = e0 + w011 * g.t3.x; e1 = e1 + w011 * g.t3.y;
    e0 = e0 + w100 * g.t4.x; e1 = e1 + w100 * g.t4.y;
    e0 = e0 + w101 * g.t5.x; e1 = e1 + w101 * g.t5.y;
    e0 = e0 + w110 * g.t6.x; e1 = e1 + w110 * g.t6.y;
    e0 = e0 + w111 * g.t7.x; e1 = e1 + w111 * g.t7.y;
    Enc2 r; r.e0 = e0; r.e1 = e1; return r;
}

// enc pair + backward coeffs (coeffs value-continuous: fmaf ok)
__device__ __forceinline__ EncA lv_enc_a(const Gather g)
{
#pragma clang fp contract(off)
    const float gx0 = 1.0f - g.fx, gx1 = g.fx;
    const float gy0 = 1.0f - g.fy, gy1 = g.fy;
    const float gz0 = 1.0f - g.fz, gz1 = g.fz;
    const float pxy00 = gx0 * gy0, pxy01 = gx0 * gy1, pxy10 = gx1 * gy0, pxy11 = gx1 * gy1;
    const float w000 = pxy00 * gz0, w001 = pxy00 * gz1, w010 = pxy01 * gz0, w011 = pxy01 * gz1;
    const float w100 = pxy10 * gz0, w101 = pxy10 * gz1, w110 = pxy11 * gz0, w111 = pxy11 * gz1;
    float e0 = 0.0f, e1 = 0.0f;
    e0 = e0 + w000 * g.t0.x; e1 = e1 + w000 * g.t0.y;
    e0 = e0 + w001 * g.t1.x; e1 = e1 + w001 * g.t1.y;
    e0 = e0 + w010 * g.t2.x; e1 = e1 + w010 * g.t2.y;
    e0 = e0 + w011 * g.t3.x; e1 = e1 + w011 * g.t3.y;
    e0 = e0 + w100 * g.t4.x; e1 = e1 + w100 * g.t4.y;
    e0 = e0 + w101 * g.t5.x; e1 = e1 + w101 * g.t5.y;
    e0 = e0 + w110 * g.t6.x; e1 = e1 + w110 * g.t6.y;
    e0 = e0 + w111 * g.t7.x; e1 = e1 + w111 * g.t7.y;
    const float pyz00 = gy0 * gz0, pyz01 = gy0 * gz1, pyz10 = gy1 * gz0, pyz11 = gy1 * gz1;
    const float pxz00 = gx0 * gz0, pxz01 = gx0 * gz1, pxz10 = gx1 * gz0, pxz11 = gx1 * gz1;
    float a0x = 0.f, a0y = 0.f, a0z = 0.f, a1x = 0.f, a1y = 0.f, a1z = 0.f;
    a0x = fmaf(-pyz00, g.t0.x, a0x); a1x = fmaf(-pyz00, g.t0.y, a1x);
    a0y = fmaf(-pxz00, g.t0.x, a0y); a1y = fmaf(-pxz00, g.t0.y, a1y);
    a0z = fmaf(-pxy00, g.t0.x, a0z); a1z = fmaf(-pxy00, g.t0.y, a1z);
    a0x = fmaf(-pyz01, g.t1.x, a0x); a1x = fmaf(-pyz01, g.t1.y, a1x);
    a0y = fmaf(-pxz01, g.t1.x, a0y); a1y = fmaf(-pxz01, g.t1.y, a1y);
    a0z = fmaf( pxy00, g.t1.x, a0z); a1z = fmaf( pxy00, g.t1.y, a1z);
    a0x = fmaf(-pyz10, g.t2.x, a0x); a1x = fmaf(-pyz10, g.t2.y, a1x);
    a0y = fmaf( pxz00, g.t2.x, a0y); a1y = fmaf( pxz00, g.t2.y, a1y);
    a0z = fmaf(-pxy01, g.t2.x, a0z); a1z = fmaf(-pxy01, g.t2.y, a1z);
    a0x = fmaf(-pyz11, g.t3.x, a0x); a1x = fmaf(-pyz11, g.t3.y, a1x);
    a0y = fmaf( pxz01, g.t3.x, a0y); a1y = fmaf( pxz01, g.t3.y, a1y);
    a0z = fmaf( pxy01, g.t3.x, a0z); a1z = fmaf( pxy01, g.t3.y, a1z);
    a0x = fmaf( pyz00, g.t4.x, a0x); a1x = fmaf( pyz00, g.t4.y, a1x);
    a0y = fmaf(-pxz10, g.t4.x, a0y); a1y = fmaf(-pxz10, g.t4.y, a1y);
    a0z = fmaf(-pxy10, g.t4.x, a0z); a1z = fmaf(-pxy10, g.t4.y, a1z);
    a0x = fmaf( pyz01, g.t5.x, a0x); a1x = fmaf( pyz01, g.t5.y, a1x);
    a0y = fmaf(-pxz11, g.t5.x, a0y); a1y = fmaf(-pxz11, g.t5.y, a1y);
    a0z = fmaf( pxy10, g.t5.x, a0z); a1z = fmaf( pxy10, g.t5.y, a1z);
    a0x = fmaf( pyz10, g.t6.x, a0x); a1x = fmaf( pyz10, g.t6.y, a1x);
    a0y = fmaf( pxz10, g.t6.x, a0y); a1y = fmaf( pxz10, g.t6.y, a1y);
    a0z = fmaf(-pxy11, g.t6.x, a0z); a1z = fmaf(-pxy11, g.t6.y, a1z);
    a0x = fmaf( pyz11, g.t7.x, a0x); a1x = fmaf( pyz11, g.t7.y, a1x);
    a0y = fmaf( pxz11, g.t7.x, a0y); a1y = fmaf( pxz11, g.t7.y, a1y);
    a0z = fmaf( pxy11, g.t7.x, a0z); a1z = fmaf( pxy11, g.t7.y, a1z);
    EncA r;
    r.e0 = e0; r.e1 = e1;
    r.a0x = a0x; r.a0y = a0y; r.a0z = a0z;
    r.a1x = a1x; r.a1y = a1y; r.a1z = a1z;
    return r;
}

// backward partial for re-gathered dense levels (fmaf ok)
__device__ __forceinline__ L3v bwd_part(const Gather g, const float g0, const float g1)
{
    const float gx0 = 1.0f - g.fx, gx1 = g.fx;
    const float gy0 = 1.0f - g.fy, gy1 = g.fy;
    const float gz0 = 1.0f - g.fz, gz1 = g.fz;
    const float pyz00 = gy0 * gz0, pyz01 = gy0 * gz1, pyz10 = gy1 * gz0, pyz11 = gy1 * gz1;
    const float pxz00 = gx0 * gz0, pxz01 = gx0 * gz1, pxz10 = gx1 * gz0, pxz11 = gx1 * gz1;
    const float pxy00 = gx0 * gy0, pxy01 = gx0 * gy1, pxy10 = gx1 * gy0, pxy11 = gx1 * gy1;
    const float s000 = fmaf(g0, g.t0.x, g1 * g.t0.y);
    const float s001 = fmaf(g0, g.t1.x, g1 * g.t1.y);
    const float s010 = fmaf(g0, g.t2.x, g1 * g.t2.y);
    const float s011 = fmaf(g0, g.t3.x, g1 * g.t3.y);
    const float s100 = fmaf(g0, g.t4.x, g1 * g.t4.y);
    const float s101 = fmaf(g0, g.t5.x, g1 * g.t5.y);
    const float s110 = fmaf(g0, g.t6.x, g1 * g.t6.y);
    const float s111 = fmaf(g0, g.t7.x, g1 * g.t7.y);
    float lx = 0.f, ly = 0.f, lz = 0.f;
    lx = fmaf(-pyz00, s000, lx); ly = fmaf(-pxz00, s000, ly); lz = fmaf(-pxy00, s000, lz);
    lx = fmaf(-pyz01, s001, lx); ly = fmaf(-pxz01, s001, ly); lz = fmaf( pxy00, s001, lz);
    lx = fmaf(-pyz10, s010, lx); ly = fmaf( pxz00, s010, ly); lz = fmaf(-pxy01, s010, lz);
    lx = fmaf(-pyz11, s011, lx); ly = fmaf( pxz01, s011, ly); lz = fmaf( pxy01, s011, lz);
    lx = fmaf( pyz00, s100, lx); ly = fmaf(-pxz10, s100, ly); lz = fmaf(-pxy10, s100, lz);
    lx = fmaf( pyz01, s101, lx); ly = fmaf(-pxz11, s101, ly); lz = fmaf( pxy10, s101, lz);
    lx = fmaf( pyz10, s110, lx); ly = fmaf( pxz10, s110, ly); lz = fmaf(-pxy11, s110, lz);
    lx = fmaf( pyz11, s111, lx); ly = fmaf( pxz11, s111, ly); lz = fmaf( pxy11, s111, lz);
    L3v r; r.lx = lx; r.ly = ly; r.lz = lz; return r;
}

__device__ __forceinline__ void clampedxn(const float* __restrict__ x, const int n,
                                          float& xn0, float& xn1, float& xn2)
{
    const float x0 = x[(size_t)n * 6 + 0];
    const float x1 = x[(size_t)n * 6 + 1];
    const float x2 = x[(size_t)n * 6 + 2];
    xn0 = fminf(fmaxf((x0 + 1.0f) * 0.5f, 0.0f), 1.0f);
    xn1 = fminf(fmaxf((x1 + 1.0f) * 0.5f, 0.0f), 1.0f);
    xn2 = fminf(fmaxf((x2 + 1.0f) * 0.5f, 0.0f), 1.0f);
}

// ============================================================================
// K1: level-phased gather, 11 phases. Phase 0 = dense levels 0-5 (~6.9MB
// tables, heavy line reuse); phases 1-10 = hashed levels 6-15 (4MB each,
// == one XCD L2). Blocks dispatch in blockIdx order -> in-flight window
// covers ~one phase -> table reads are L2 hits.
// ============================================================================
__global__ __launch_bounds__(256) __attribute__((amdgpu_waves_per_eu(8, 8)))
void k_gather_phased(const float* __restrict__ x, const float* __restrict__ tables,
                     float* __restrict__ ws, Params P)
{
    const int ph = blockIdx.x >> 11;                       // 2048 blocks/phase
    const int n = ((blockIdx.x & 2047) << 8) + threadIdx.x;
    if (n >= N_POINTS) return;
    const size_t N = (size_t)N_POINTS;
    float xn0, xn1, xn2;
    clampedxn(x, n, xn0, xn1, xn2);
    const float2* __restrict__ tb = (const float2*)tables;
    float* __restrict__ we = ws;               // [32][N] enc
    float* __restrict__ wa = ws + 32 * N;      // [66][N] A coeffs (c*NA + i)

#define ST_E(L, R) { we[(size_t)(2*(L))*N + n] = R.e0; we[(size_t)(2*(L)+1)*N + n] = R.e1; }
#define ST_A(L, R) { const int i_ = (L) - ASTART;                         \
        wa[(size_t)(0*NA + i_)*N + n] = R.a0x;                            \
        wa[(size_t)(1*NA + i_)*N + n] = R.a0y;                            \
        wa[(size_t)(2*NA + i_)*N + n] = R.a0z;                            \
        wa[(size_t)(3*NA + i_)*N + n] = R.a1x;                            \
        wa[(size_t)(4*NA + i_)*N + n] = R.a1y;                            \
        wa[(size_t)(5*NA + i_)*N + n] = R.a1z; }

    if (ph == 0) {
        // dense levels 0-5, paired issue for MLP
        {
            const Gather gA = lv_issue_rt(tb + 0 * (size_t)TSZ, P.res[0], false, xn0, xn1, xn2);
            const Gather gB = lv_issue_rt(tb + 1 * (size_t)TSZ, P.res[1], false, xn0, xn1, xn2);
            const Enc2 rA = lv_enc(gA); ST_E(0, rA)
            const Enc2 rB = lv_enc(gB); ST_E(1, rB)
        }
        {
            const Gather gA = lv_issue_rt(tb + 2 * (size_t)TSZ, P.res[2], false, xn0, xn1, xn2);
            const Gather gB = lv_issue_rt(tb + 3 * (size_t)TSZ, P.res[3], false, xn0, xn1, xn2);
            const Enc2 rA = lv_enc(gA); ST_E(2, rA)
            const Enc2 rB = lv_enc(gB); ST_E(3, rB)
        }
        {
            const Gather gA = lv_issue_rt(tb + 4 * (size_t)TSZ, P.res[4], false, xn0, xn1, xn2);
            const Gather gB = lv_issue_rt(tb + 5 * (size_t)TSZ, P.res[5], false, xn0, xn1, xn2);
            const Enc2 rA = lv_enc(gA); ST_E(4, rA)
            const EncA rB = lv_enc_a(gB); ST_E(5, rB) ST_A(5, rB)
        }
    } else {
        const int lvl = 5 + ph;                            // 6..15, all hashed
        const Gather g = lv_issue_rt(tb + (size_t)lvl * TSZ, P.res[lvl], true, xn0, xn1, xn2);
        const EncA r = lv_enc_a(g);
        ST_E(lvl, r)
        ST_A(lvl, r)
    }
#undef ST_E
#undef ST_A
}

// ============================================================================
// K2a: density MLP only. enc loaded coalesced; writes sigma/geo/wgeo and the
// relu mask into the (already consumed) enc[0..2) rows of ws. Live ~60 regs,
// waves(6,8) for 6-8 waves/EU.
// ============================================================================
__global__ __launch_bounds__(256) __attribute__((amdgpu_waves_per_eu(6, 8)))
void k_dmlp(const float* __restrict__ x,
            const float* __restrict__ w_s0, const float* __restrict__ w_s1,
            float* __restrict__ ws, float* __restrict__ wgeo,
            float* __restrict__ out)
{
    const int n = blockIdx.x * 256 + threadIdx.x;
    if (n >= N_POINTS) return;
    const size_t N = (size_t)N_POINTS;
    float* __restrict__ we = ws;

    float enc[32];
    #pragma unroll
    for (int j = 0; j < 32; ++j) enc[j] = we[(size_t)j * N + n];

    // ---- density MLP (verbatim, bit-exact mul/add order) ----
    float hd[16];
    #pragma unroll
    for (int m = 0; m < 16; ++m) hd[m] = 0.0f;
    unsigned long long mask = 0ull;
    {
        #pragma clang fp contract(off)
        for (int k = 0; k < 64; ++k) {
            float a = 0.0f;
            #pragma unroll
            for (int j = 0; j < 32; ++j) {
                const float p = enc[j] * w_s0[j * 64 + k];
                a = a + p;
            }
            const float hr = fmaxf(a, 0.0f);
            #pragma unroll
            for (int m = 0; m < 16; ++m) hd[m] = fmaf(hr, w_s1[k * 16 + m], hd[m]);
            if (a > 0.0f) mask |= (1ull << k);
        }
    }

    out[n] = hd[0];
    #pragma unroll
    for (int j = 0; j < 15; ++j) {
        out[N + (size_t)n * 15 + j] = hd[1 + j];
        wgeo[(size_t)j * N + n] = hd[1 + j];
    }
    // mask -> ws rows 0,1 (enc fully consumed; each thread touches only slot n)
    we[(size_t)0 * N + n] = __uint_as_float((unsigned)(mask & 0xffffffffull));
    we[(size_t)1 * N + n] = __uint_as_float((unsigned)(mask >> 32));
}

// ============================================================================
// K2b: genc + backward gradient + true normal. Reads mask from ws rows 0,1.
// Live ~80 regs, waves(4,8).
// ============================================================================
__global__ __launch_bounds__(256) __attribute__((amdgpu_waves_per_eu(4, 8)))
void k_bwd(const float* __restrict__ x, const float* __restrict__ tables,
           const float* __restrict__ w_s0, const float* __restrict__ w_s1,
           const float* __restrict__ ws, float* __restrict__ out, Params P)
{
    const int n = blockIdx.x * 256 + threadIdx.x;
    if (n >= N_POINTS) return;
    const size_t N = (size_t)N_POINTS;
    float xn0, xn1, xn2;
    clampedxn(x, n, xn0, xn1, xn2);
    const float2* __restrict__ tb = (const float2*)tables;
    const float* __restrict__ we = ws;
    const float* __restrict__ wa = ws + 32 * N;

    const unsigned mlo = __float_as_uint(we[(size_t)0 * N + n]);
    const unsigned mhi = __float_as_uint(we[(size_t)1 * N + n]);
    const unsigned long long mask = ((unsigned long long)mhi << 32) | mlo;

    // ---- genc[32] = ws0 @ (mask .* ws1[:,0]) ----
    float genc[32];
    #pragma unroll
    for (int j = 0; j < 32; ++j) genc[j] = 0.0f;
    for (int k = 0; k < 64; ++k) {
        const float ghk = ((mask >> k) & 1ull) ? w_s1[k * 16] : 0.0f;
        #pragma unroll
        for (int j = 0; j < 32; ++j) genc[j] = fmaf(w_s0[j * 64 + k], ghk, genc[j]);
    }

    // ---- dense levels 0-4 re-gathered in pairs (L2-hot tiny tables) ----
    float gx = 0.0f, gy = 0.0f, gz = 0.0f;
    {
        const Gather gA = lv_issue<false>(tb + 0 * (size_t)TSZ, P.res[0], xn0, xn1, xn2);
        const Gather gB = lv_issue<false>(tb + 1 * (size_t)TSZ, P.res[1], xn0, xn1, xn2);
        {
            const L3v d = bwd_part(gA, genc[0], genc[1]);
            const float rf = (float)(P.res[0] - 1);
            gx = fmaf(d.lx, rf, gx); gy = fmaf(d.ly, rf, gy); gz = fmaf(d.lz, rf, gz);
        }
        {
            const L3v d = bwd_part(gB, genc[2], genc[3]);
            const float rf = (float)(P.res[1] - 1);
            gx = fmaf(d.lx, rf, gx); gy = fmaf(d.ly, rf, gy); gz = fmaf(d.lz, rf, gz);
        }
    }
    {
        const Gather gA = lv_issue<false>(tb + 2 * (size_t)TSZ, P.res[2], xn0, xn1, xn2);
        const Gather gB = lv_issue<false>(tb + 3 * (size_t)TSZ, P.res[3], xn0, xn1, xn2);
        {
            const L3v d = bwd_part(gA, genc[4], genc[5]);
            const float rf = (float)(P.res[2] - 1);
            gx = fmaf(d.lx, rf, gx); gy = fmaf(d.ly, rf, gy); gz = fmaf(d.lz, rf, gz);
        }
        {
            const L3v d = bwd_part(gB, genc[6], genc[7]);
            const float rf = (float)(P.res[3] - 1);
            gx = fmaf(d.lx, rf, gx); gy = fmaf(d.ly, rf, gy); gz = fmaf(d.lz, rf, gz);
        }
    }
    {
        const Gather gA = lv_issue<false>(tb + 4 * (size_t)TSZ, P.res[4], xn0, xn1, xn2);
        const L3v d = bwd_part(gA, genc[8], genc[9]);
        const float rf = (float)(P.res[4] - 1);
        gx = fmaf(d.lx, rf, gx); gy = fmaf(d.ly, rf, gy); gz = fmaf(d.lz, rf, gz);
    }

    // ---- high levels: stream A from ws (coalesced; static i via unroll) ----
    #pragma unroll
    for (int l = ASTART; l < NLV; ++l) {
        const int i = l - ASTART;
        const float rf = (float)(P.res[l] - 1);
        const float g0 = genc[2 * l], g1 = genc[2 * l + 1];
        const float a0x = wa[(size_t)(0*NA + i)*N + n];
        const float a0y = wa[(size_t)(1*NA + i)*N + n];
        const float a0z = wa[(size_t)(2*NA + i)*N + n];
        const float a1x = wa[(size_t)(3*NA + i)*N + n];
        const float a1y = wa[(size_t)(4*NA + i)*N + n];
        const float a1z = wa[(size_t)(5*NA + i)*N + n];
        gx = fmaf(rf, fmaf(g0, a0x, g1 * a1x), gx);
        gy = fmaf(rf, fmaf(g0, a0y, g1 * a1y), gy);
        gz = fmaf(rf, fmaf(g0, a0z, g1 * a1z), gz);
    }
    gx *= 0.5f; gy *= 0.5f; gz *= 0.5f;

    const float gnorm = sqrtf(gx * gx + gy * gy + gz * gz);
    const float ginv = 1.0f / fmaxf(gnorm, 1e-8f);

    out[16 * N + (size_t)n * 3 + 0] = -gx * ginv;
    out[16 * N + (size_t)n * 3 + 1] = -gy * ginv;
    out[16 * N + (size_t)n * 3 + 2] = -gz * ginv;
}

// ============================================================================
// K2c: pred_normal + mirror + color MLP. Control: unchanged from R11.
// ============================================================================
__global__ __launch_bounds__(256) __attribute__((amdgpu_waves_per_eu(4, 4)))
void k_color(const float* __restrict__ x,
             const float* __restrict__ wc0, const float* __restrict__ wc1,
             const float* __restrict__ wc2,
             const float* __restrict__ wn0, const float* __restrict__ wn1,
             const float* __restrict__ wm0, const float* __restrict__ bm0,
             const float* __restrict__ wm1, const float* __restrict__ bm1,
             const float* __restrict__ wgeo, float* __restrict__ out)
{
    const int n = blockIdx.x * 256 + threadIdx.x;
    if (n >= N_POINTS) return;
    const size_t N = (size_t)N_POINTS;

    float geo[15];
    #pragma unroll
    for (int j = 0; j < 15; ++j) geo[j] = wgeo[(size_t)j * N + n];

    // ---- pred_normal = l2_normalize(relu(geo @ wn0) @ wn1) ----
    float pn0 = 0.0f, pn1 = 0.0f, pn2 = 0.0f;
    for (int k = 0; k < 64; ++k) {
        float a = 0.0f;
        #pragma unroll
        for (int j = 0; j < 15; ++j) a = fmaf(geo[j], wn0[j * 64 + k], a);
        a = fmaxf(a, 0.0f);
        pn0 = fmaf(a, wn1[k * 3 + 0], pn0);
        pn1 = fmaf(a, wn1[k * 3 + 1], pn1);
        pn2 = fmaf(a, wn1[k * 3 + 2], pn2);
    }
    const float pnorm = sqrtf(pn0 * pn0 + pn1 * pn1 + pn2 * pn2);
    const float pinv = 1.0f / fmaxf(pnorm, 1e-8f);
    out[19 * N + (size_t)n * 3 + 0] = pn0 * pinv;
    out[19 * N + (size_t)n * 3 + 1] = pn1 * pinv;
    out[19 * N + (size_t)n * 3 + 2] = pn2 * pinv;

    // ---- mirror head ----
    float macc = 0.0f;
    for (int k = 0; k < 32; ++k) {
        float a = bm0[k];
        #pragma unroll
        for (int j = 0; j < 15; ++j) a = fmaf(geo[j], wm0[j * 32 + k], a);
        a = (a >= 0.0f) ? a : 0.01f * a;
        macc = fmaf(a, wm1[k], macc);
    }
    macc += bm1[0];
    out[25 * N + n] = 1.0f / (1.0f + expf(-macc));

    // ---- spherical harmonics of d ----
    const float dx = x[(size_t)n * 6 + 3];
    const float dy = x[(size_t)n * 6 + 4];
    const float dz = x[(size_t)n * 6 + 5];
    float sh[16];
    const float xy = dx * dy, xz = dx * dz, yz = dy * dz;
    const float x2s = dx * dx, y2s = dy * dy, z2s = dz * dz;
    sh[0]  = 0.28209479177387814f;
    sh[1]  = -0.48860251190291987f * dy;
    sh[2]  =  0.48860251190291987f * dz;
    sh[3]  = -0.48860251190291987f * dx;
    sh[4]  =  1.0925484305920792f * xy;
    sh[5]  = -1.0925484305920792f * yz;
    sh[6]  =  0.94617469575756f * z2s - 0.31539156525252005f;
    sh[7]  = -1.0925484305920792f * xz;
    sh[8]  =  0.5462742152960396f * (x2s - y2s);
    sh[9]  =  0.5900435899266435f * dy * (-3.0f * x2s + y2s);
    sh[10] =  2.890611442640554f * xy * dz;
    sh[11] =  0.4570457994644657f * dy * (1.0f - 5.0f * z2s);
    sh[12] =  0.3731763325901154f * dz * (5.0f * z2s - 3.0f);
    sh[13] =  0.4570457994644657f * dx * (1.0f - 5.0f * z2s);
    sh[14] =  1.445305721320277f * dz * (x2s - y2s);
    sh[15] =  0.5900435899266435f * dx * (x2s - 3.0f * y2s);

    // ---- color MLP: [sh, geo] (31) -> 64 -> 64 -> 3, sigmoid ----
    float cacc[64];
    #pragma unroll
    for (int k = 0; k < 64; ++k) cacc[k] = 0.0f;
    for (int kc = 0; kc < 64; ++kc) {
        float a = 0.0f;
        #pragma unroll
        for (int j = 0; j < 16; ++j) a = fmaf(sh[j], wc0[j * 64 + kc], a);
        #pragma unroll
        for (int j = 0; j < 15; ++j) a = fmaf(geo[j], wc0[(16 + j) * 64 + kc], a);
        const float c1v = fmaxf(a, 0.0f);
        const float* __restrict__ wrow = wc1 + kc * 64;
        #pragma unroll
        for (int k2 = 0; k2 < 64; ++k2) cacc[k2] = fmaf(c1v, wrow[k2], cacc[k2]);
    }
    float r0 = 0.0f, r1 = 0.0f, r2 = 0.0f;
    #pragma unroll
    for (int k = 0; k < 64; ++k) {
        const float a = fmaxf(cacc[k], 0.0f);
        r0 = fmaf(a, wc2[k * 3 + 0], r0);
        r1 = fmaf(a, wc2[k * 3 + 1], r1);
        r2 = fmaf(a, wc2[k * 3 + 2], r2);
    }
    out[22 * N + (size_t)n * 3 + 0] = 1.0f / (1.0f + expf(-r0));
    out[22 * N + (size_t)n * 3 + 1] = 1.0f / (1.0f + expf(-r1));
    out[22 * N + (size_t)n * 3 + 2] = 1.0f / (1.0f + expf(-r2));
}

// ============================================================================
// Fallback: R5 mono kernel (verified passing) — used if ws too small.
// ============================================================================
__global__ __launch_bounds__(256) __attribute__((amdgpu_waves_per_eu(3, 4)))
void nerf_mono(const float* __restrict__ x, const float* __restrict__ tables,
               const float* __restrict__ w_s0, const float* __restrict__ w_s1,
               const float* __restrict__ wc0, const float* __restrict__ wc1,
               const float* __restrict__ wc2, const float* __restrict__ wn0,
               const float* __restrict__ wn1, const float* __restrict__ wm0,
               const float* __restrict__ bm0, const float* __restrict__ wm1,
               const float* __restrict__ bm1, float* __restrict__ out, Params P)
{
    const int n = blockIdx.x * 256 + threadIdx.x;
    if (n >= N_POINTS) return;
    float xn0, xn1, xn2;
    clampedxn(x, n, xn0, xn1, xn2);
    const float2* __restrict__ tb = (const float2*)tables;

    float enc[32];
    float A0x[NA], A0y[NA], A0z[NA], A1x[NA], A1y[NA], A1z[NA];

#define MPAIR_NN(LA, LB) {                                                             \
        const Gather gA = lv_issue<false>(tb + (size_t)(LA)*TSZ, P.res[LA], xn0, xn1, xn2); \
        const Gather gB = lv_issue<false>(tb + (size_t)(LB)*TSZ, P.res[LB], xn0, xn1, xn2); \
        const Enc2 rA = lv_enc(gA); enc[2*(LA)] = rA.e0; enc[2*(LA)+1] = rA.e1;        \
        const Enc2 rB = lv_enc(gB); enc[2*(LB)] = rB.e0; enc[2*(LB)+1] = rB.e1; }
#define MPAIR_NA(LA, LB) {                                                             \
        const Gather gA = lv_issue<false>(tb + (size_t)(LA)*TSZ, P.res[LA], xn0, xn1, xn2); \
        const Gather gB = lv_issue<false>(tb + (size_t)(LB)*TSZ, P.res[LB], xn0, xn1, xn2); \
        const Enc2 rA = lv_enc(gA); enc[2*(LA)] = rA.e0; enc[2*(LA)+1] = rA.e1;        \
        const EncA rB = lv_enc_a(gB); enc[2*(LB)] = rB.e0; enc[2*(LB)+1] = rB.e1;      \
        A0x[(LB)-ASTART] = rB.a0x; A0y[(LB)-ASTART] = rB.a0y; A0z[(LB)-ASTART] = rB.a0z; \
        A1x[(LB)-ASTART] = rB.a1x; A1y[(LB)-ASTART] = rB.a1y; A1z[(LB)-ASTART] = rB.a1z; }
#define MPAIR_AA(LA, LB) {                                                             \
        const Gather gA = lv_issue<true>(tb + (size_t)(LA)*TSZ, P.res[LA], xn0, xn1, xn2);  \
        const Gather gB = lv_issue<true>(tb + (size_t)(LB)*TSZ, P.res[LB], xn0, xn1, xn2);  \
        const EncA rA = lv_enc_a(gA); enc[2*(LA)] = rA.e0; enc[2*(LA)+1] = rA.e1;      \
        A0x[(LA)-ASTART] = rA.a0x; A0y[(LA)-ASTART] = rA.a0y; A0z[(LA)-ASTART] = rA.a0z; \
        A1x[(LA)-ASTART] = rA.a1x; A1y[(LA)-ASTART] = rA.a1y; A1z[(LA)-ASTART] = rA.a1z; \
        const EncA rB = lv_enc_a(gB); enc[2*(LB)] = rB.e0; enc[2*(LB)+1] = rB.e1;      \
        A0x[(LB)-ASTART] = rB.a0x; A0y[(LB)-ASTART] = rB.a0y; A0z[(LB)-ASTART] = rB.a0z; \
        A1x[(LB)-ASTART] = rB.a1x; A1y[(LB)-ASTART] = rB.a1y; A1z[(LB)-ASTART] = rB.a1z; }

    MPAIR_NN(0, 1)
    MPAIR_NN(2, 3)
    MPAIR_NA(4, 5)
    MPAIR_AA(6, 7)
    MPAIR_AA(8, 9)
    MPAIR_AA(10, 11)
    MPAIR_AA(12, 13)
    MPAIR_AA(14, 15)
#undef MPAIR_NN
#undef MPAIR_NA
#undef MPAIR_AA

    float hd[16];
    #pragma unroll
    for (int m = 0; m < 16; ++m) hd[m] = 0.0f;
    unsigned long long mask = 0ull;
    {
        #pragma clang fp contract(off)
        for (int k = 0; k < 64; ++k) {
            float a = 0.0f;
            #pragma unroll
            for (int j = 0; j < 32; ++j) {
                const float p = enc[j] * w_s0[j * 64 + k];
                a = a + p;
            }
            const float hr = fmaxf(a, 0.0f);
            #pragma unroll
            for (int m = 0; m < 16; ++m) hd[m] = fmaf(hr, w_s1[k * 16 + m], hd[m]);
            if (a > 0.0f) mask |= (1ull << k);
        }
    }
    const float sigma = hd[0];

    float gx = 0.0f, gy = 0.0f, gz = 0.0f;
    {
        const Gather g0v = lv_issue<false>(tb + 0 * (size_t)TSZ, P.res[0], xn0, xn1, xn2);
        const Gather g1v = lv_issue<false>(tb + 1 * (size_t)TSZ, P.res[1], xn0, xn1, xn2);

        float genc[32];
        #pragma unroll
        for (int j = 0; j < 32; ++j) genc[j] = 0.0f;
        for (int k = 0; k < 64; ++k) {
            const float ghk = ((mask >> k) & 1ull) ? w_s1[k * 16] : 0.0f;
            #pragma unroll
            for (int j = 0; j < 32; ++j) genc[j] = fmaf(w_s0[j * 64 + k], ghk, genc[j]);
        }

        {
            const L3v d = bwd_part(g0v, genc[0], genc[1]);
            const float rf = (float)(P.res[0] - 1);
            gx = fmaf(d.lx, rf, gx); gy = fmaf(d.ly, rf, gy); gz = fmaf(d.lz, rf, gz);
        }
        {
            const L3v d = bwd_part(g1v, genc[2], genc[3]);
            const float rf = (float)(P.res[1] - 1);
            gx = fmaf(d.lx, rf, gx); gy = fmaf(d.ly, rf, gy); gz = fmaf(d.lz, rf, gz);
        }
        {
            const Gather g2v = lv_issue<false>(tb + 2 * (size_t)TSZ, P.res[2], xn0, xn1, xn2);
            const Gather g3v = lv_issue<false>(tb + 3 * (size_t)TSZ, P.res[3], xn0, xn1, xn2);
            {
                const L3v d = bwd_part(g2v, genc[4], genc[5]);
                const float rf = (float)(P.res[2] - 1);
                gx = fmaf(d.lx, rf, gx); gy = fmaf(d.ly, rf, gy); gz = fmaf(d.lz, rf, gz);
            }
            {
                const L3v d = bwd_part(g3v, genc[6], genc[7]);
                const float rf = (float)(P.res[3] - 1);
                gx = fmaf(d.lx, rf, gx); gy = fmaf(d.ly, rf, gy); gz = fmaf(d.lz, rf, gz);
            }
        }
        {
            const Gather g4v = lv_issue<false>(tb + 4 * (size_t)TSZ, P.res[4], xn0, xn1, xn2);
            const L3v d = bwd_part(g4v, genc[8], genc[9]);
            const float rf = (float)(P.res[4] - 1);
            gx = fmaf(d.lx, rf, gx); gy = fmaf(d.ly, rf, gy); gz = fmaf(d.lz, rf, gz);
        }

        #pragma unroll
        for (int l = ASTART; l < NLV; ++l) {
            const int i = l - ASTART;
            const float rf = (float)(P.res[l] - 1);
            const float g0 = genc[2 * l], g1 = genc[2 * l + 1];
            gx = fmaf(rf, fmaf(g0, A0x[i], g1 * A1x[i]), gx);
            gy = fmaf(rf, fmaf(g0, A0y[i], g1 * A1y[i]), gy);
            gz = fmaf(rf, fmaf(g0, A0z[i], g1 * A1z[i]), gz);
        }
    }
    gx *= 0.5f; gy *= 0.5f; gz *= 0.5f;

    const float gnorm = sqrtf(gx * gx + gy * gy + gz * gz);
    const float ginv = 1.0f / fmaxf(gnorm, 1e-8f);

    float geo[15];
    #pragma unroll
    for (int j = 0; j < 15; ++j) geo[j] = hd[1 + j];

    float pn0 = 0.0f, pn1 = 0.0f, pn2 = 0.0f;
    for (int k = 0; k < 64; ++k) {
        float a = 0.0f;
        #pragma unroll
        for (int j = 0; j < 15; ++j) a = fmaf(geo[j], wn0[j * 64 + k], a);
        a = fmaxf(a, 0.0f);
        pn0 = fmaf(a, wn1[k * 3 + 0], pn0);
        pn1 = fmaf(a, wn1[k * 3 + 1], pn1);
        pn2 = fmaf(a, wn1[k * 3 + 2], pn2);
    }
    const float pnorm = sqrtf(pn0 * pn0 + pn1 * pn1 + pn2 * pn2);
    const float pinv = 1.0f / fmaxf(pnorm, 1e-8f);

    const float dx = x[(size_t)n * 6 + 3];
    const float dy = x[(size_t)n * 6 + 4];
    const float dz = x[(size_t)n * 6 + 5];
    float sh[16];
    const float xy = dx * dy, xz = dx * dz, yz = dy * dz;
    const float x2s = dx * dx, y2s = dy * dy, z2s = dz * dz;
    sh[0]  = 0.28209479177387814f;
    sh[1]  = -0.48860251190291987f * dy;
    sh[2]  =  0.48860251190291987f * dz;
    sh[3]  = -0.48860251190291987f * dx;
    sh[4]  =  1.0925484305920792f * xy;
    sh[5]  = -1.0925484305920792f * yz;
    sh[6]  =  0.94617469575756f * z2s - 0.31539156525252005f;
    sh[7]  = -1.0925484305920792f * xz;
    sh[8]  =  0.5462742152960396f * (x2s - y2s);
    sh[9]  =  0.5900435899266435f * dy * (-3.0f * x2s + y2s);
    sh[10] =  2.890611442640554f * xy * dz;
    sh[11] =  0.4570457994644657f * dy * (1.0f - 5.0f * z2s);
    sh[12] =  0.3731763325901154f * dz * (5.0f * z2s - 3.0f);
    sh[13] =  0.4570457994644657f * dx * (1.0f - 5.0f * z2s);
    sh[14] =  1.445305721320277f * dz * (x2s - y2s);
    sh[15] =  0.5900435899266435f * dx * (x2s - 3.0f * y2s);

    float cacc[64];
    #pragma unroll
    for (int k = 0; k < 64; ++k) cacc[k] = 0.0f;
    for (int kc = 0; kc < 64; ++kc) {
        float a = 0.0f;
        #pragma unroll
        for (int j = 0; j < 16; ++j) a = fmaf(sh[j], wc0[j * 64 + kc], a);
        #pragma unroll
        for (int j = 0; j < 15; ++j) a = fmaf(geo[j], wc0[(16 + j) * 64 + kc], a);
        const float c1v = fmaxf(a, 0.0f);
        const float* __restrict__ wrow = wc1 + kc * 64;
        #pragma unroll
        for (int k2 = 0; k2 < 64; ++k2) cacc[k2] = fmaf(c1v, wrow[k2], cacc[k2]);
    }
    float r0 = 0.0f, r1 = 0.0f, r2 = 0.0f;
    #pragma unroll
    for (int k = 0; k < 64; ++k) {
        const float a = fmaxf(cacc[k], 0.0f);
        r0 = fmaf(a, wc2[k * 3 + 0], r0);
        r1 = fmaf(a, wc2[k * 3 + 1], r1);
        r2 = fmaf(a, wc2[k * 3 + 2], r2);
    }
    const float rgb0 = 1.0f / (1.0f + expf(-r0));
    const float rgb1 = 1.0f / (1.0f + expf(-r1));
    const float rgb2 = 1.0f / (1.0f + expf(-r2));

    float macc = 0.0f;
    for (int k = 0; k < 32; ++k) {
        float a = bm0[k];
        #pragma unroll
        for (int j = 0; j < 15; ++j) a = fmaf(geo[j], wm0[j * 32 + k], a);
        a = (a >= 0.0f) ? a : 0.01f * a;
        macc = fmaf(a, wm1[k], macc);
    }
    macc += bm1[0];
    const float mir = 1.0f / (1.0f + expf(-macc));

    const size_t N = (size_t)N_POINTS;
    out[n] = sigma;
    #pragma unroll
    for (int j = 0; j < 15; ++j)
        out[N + (size_t)n * 15 + j] = geo[j];
    out[16 * N + (size_t)n * 3 + 0] = -gx * ginv;
    out[16 * N + (size_t)n * 3 + 1] = -gy * ginv;
    out[16 * N + (size_t)n * 3 + 2] = -gz * ginv;
    out[19 * N + (size_t)n * 3 + 0] = pn0 * pinv;
    out[19 * N + (size_t)n * 3 + 1] = pn1 * pinv;
    out[19 * N + (size_t)n * 3 + 2] = pn2 * pinv;
    out[22 * N + (size_t)n * 3 + 0] = rgb0;
    out[22 * N + (size_t)n * 3 + 1] = rgb1;
    out[22 * N + (size_t)n * 3 + 2] = rgb2;
    out[25 * N + n] = mir;
}

extern "C" void kernel_launch(void* const* d_in, const int* in_sizes, int n_in,
                              void* d_out, int out_size, void* d_ws, size_t ws_size,
                              hipStream_t stream)
{
    // Replicate Python's RES computation bit-for-bit:
    // PLS = exp2(log2(2048.0*BOUND/N_LEVELS)/(N_LEVELS-1)); RES[l] = floor(16*PLS**l)
    Params P;
    const double PLS = exp2(log2(2048.0 * 1.0 / 16.0) / 15.0);
    for (int l = 0; l < NLV; ++l)
        P.res[l] = (int)floor(16.0 * pow(PLS, (double)l));

    const float* x      = (const float*)d_in[0];
    const float* tables = (const float*)d_in[1];
    const float* w_s0   = (const float*)d_in[2];
    const float* w_s1   = (const float*)d_in[3];
    const float* wc0    = (const float*)d_in[4];
    const float* wc1    = (const float*)d_in[5];
    const float* wc2    = (const float*)d_in[6];
    const float* wn0    = (const float*)d_in[7];
    const float* wn1    = (const float*)d_in[8];
    const float* wm0    = (const float*)d_in[9];
    const float* bm0    = (const float*)d_in[10];
    const float* wm1    = (const float*)d_in[11];
    const float* bm1    = (const float*)d_in[12];
    float* out = (float*)d_out;

    const size_t N = (size_t)N_POINTS;
    const size_t need = (size_t)(32 + 66 + 15) * N * sizeof(float);   // 237 MB

    if (d_ws != nullptr && ws_size >= need) {
        float* ws   = (float*)d_ws;             // [32][N] enc + [66][N] A
        float* wgeo = ws + (size_t)98 * N;      // [15][N] geo
        k_gather_phased<<<NPH * (N_POINTS / 256), 256, 0, stream>>>(x, tables, ws, P);
        k_dmlp <<<N_POINTS / 256, 256, 0, stream>>>(x, w_s0, w_s1, ws, wgeo, out);
        k_bwd  <<<N_POINTS / 256, 256, 0, stream>>>(x, tables, w_s0, w_s1, ws, out, P);
        k_color<<<N_POINTS / 256, 256, 0, stream>>>(x, wc0, wc1, wc2,
                                                    wn0, wn1, wm0, bm0, wm1, bm1,
                                                    wgeo, out);
    } else {
        nerf_mono<<<N_POINTS / 256, 256, 0, stream>>>(x, tables, w_s0, w_s1,
                                                      wc0, wc1, wc2, wn0, wn1,
                                                      wm0, bm0, wm1, bm1, out, P);
    }
}

// Round 13
// 745.742 us; speedup vs baseline: 1.0648x; 1.0648x over previous
//
#include <hip/hip_runtime.h>
#include <math.h>

#define N_POINTS 524288
#define NLV      16
#define TSZ      524288
#define TMASK    (TSZ - 1)
#define ASTART   5                  // levels >= ASTART: backward via stored coeffs
#define NA       (NLV - ASTART)     // 11

static_assert(NA == 11, "NA mismatch");

struct Params { int res[NLV]; };

// ============================================================================
// R13: (1) gather reverted to R11's 16-phase form (R12's merged dense phase
//     broke the "phase working set <= 4MB XCD L2" invariant: FETCH 483->526MB,
//     306->317us). (2) k_density: MLP+genc fused into ONE k-loop (one ws0
//     traversal; genc order preserved -> bit-identical) + ws0/ws1 staged in
//     LDS (12KB) — converts per-iteration strided s_loads (~250cy) into
//     back-to-back LDS broadcasts (~60cy). (3) k_color: strided weights
//     (wc0, wn0, wm0) staged in LDS (13.7KB); wc1 rows contiguous, stay global.
// Prediction: density side 477 -> ~300-370us if SMEM-latency theory right.
// ============================================================================

struct Gather {                      // one level's 8 corner texels + fracs
    float2 t0, t1, t2, t3, t4, t5, t6, t7;
    float fx, fy, fz;
};
struct Enc2 { float e0, e1; };
struct EncA { float e0, e1, a0x, a0y, a0z, a1x, a1y, a1z; };
struct L3v  { float lx, ly, lz; };

// runtime-branch issue (wave-uniform branch)
__device__ __forceinline__ Gather lv_issue_rt(const float2* __restrict__ lt, const int res,
                                              const bool hashed,
                                              const float xn0, const float xn1, const float xn2)
{
#pragma clang fp contract(off)
    Gather g;
    const float rf = (float)(res - 1);
    const float px = xn0 * rf, py = xn1 * rf, pz = xn2 * rf;
    const float bx = floorf(px), by = floorf(py), bz = floorf(pz);
    g.fx = px - bx; g.fy = py - by; g.fz = pz - bz;
    const int r1 = res - 1;
    const int ix = (int)bx, iy = (int)by, iz = (int)bz;
    const int cx0 = min(max(ix, 0), r1),     cx1 = min(max(ix + 1, 0), r1);
    const int cy0 = min(max(iy, 0), r1),     cy1 = min(max(iy + 1, 0), r1);
    const int cz0 = min(max(iz, 0), r1),     cz1 = min(max(iz + 1, 0), r1);
    unsigned i000, i001, i010, i011, i100, i101, i110, i111;
    if (hashed) {
        const unsigned hx0 = (unsigned)cx0, hx1 = (unsigned)cx1;
        const unsigned hy0 = (unsigned)cy0 * 2654435761u, hy1 = (unsigned)cy1 * 2654435761u;
        const unsigned hz0 = (unsigned)cz0 * 805459861u,  hz1 = (unsigned)cz1 * 805459861u;
        const unsigned e00 = hy0 ^ hz0, e01 = hy0 ^ hz1, e10 = hy1 ^ hz0, e11 = hy1 ^ hz1;
        i000 = (hx0 ^ e00) & TMASK; i001 = (hx0 ^ e01) & TMASK;
        i010 = (hx0 ^ e10) & TMASK; i011 = (hx0 ^ e11) & TMASK;
        i100 = (hx1 ^ e00) & TMASK; i101 = (hx1 ^ e01) & TMASK;
        i110 = (hx1 ^ e10) & TMASK; i111 = (hx1 ^ e11) & TMASK;
    } else {
        const int b00 = res * (cy0 + res * cz0), b01 = res * (cy0 + res * cz1);
        const int b10 = res * (cy1 + res * cz0), b11 = res * (cy1 + res * cz1);
        i000 = (unsigned)(cx0 + b00); i001 = (unsigned)(cx0 + b01);
        i010 = (unsigned)(cx0 + b10); i011 = (unsigned)(cx0 + b11);
        i100 = (unsigned)(cx1 + b00); i101 = (unsigned)(cx1 + b01);
        i110 = (unsigned)(cx1 + b10); i111 = (unsigned)(cx1 + b11);
    }
    // corner order c=0..7 (ox=c>>2, oy=(c>>1)&1, oz=c&1)
    g.t0 = lt[i000]; g.t1 = lt[i001]; g.t2 = lt[i010]; g.t3 = lt[i011];
    g.t4 = lt[i100]; g.t5 = lt[i101]; g.t6 = lt[i110]; g.t7 = lt[i111];
    return g;
}

template<bool HASHED>
__device__ __forceinline__ Gather lv_issue(const float2* __restrict__ lt, const int res,
                                           const float xn0, const float xn1, const float xn2)
{
    return lv_issue_rt(lt, res, HASHED, xn0, xn1, xn2);
}

// enc pair only — bit-exact order (separate mul/add, corner order c=0..7)
__device__ __forceinline__ Enc2 lv_enc(const Gather g)
{
#pragma clang fp contract(off)
    const float gx0 = 1.0f - g.fx, gx1 = g.fx;
    const float gy0 = 1.0f - g.fy, gy1 = g.fy;
    const float gz0 = 1.0f - g.fz, gz1 = g.fz;
    const float pxy00 = gx0 * gy0, pxy01 = gx0 * gy1, pxy10 = gx1 * gy0, pxy11 = gx1 * gy1;
    const float w000 = pxy00 * gz0, w001 = pxy00 * gz1, w010 = pxy01 * gz0, w011 = pxy01 * gz1;
    const float w100 = pxy10 * gz0, w101 = pxy10 * gz1, w110 = pxy11 * gz0, w111 = pxy11 * gz1;
    float e0 = 0.0f, e1 = 0.0f;
    e0 = e0 + w000 * g.t0.x; e1 = e1 + w000 * g.t0.y;
    e0 = e0 + w001 * g.t1.x; e1 = e1 + w001 * g.t1.y;
    e0 = e0 + w010 * g.t2.x; e1 = e1 + w010 * g.t2.y;
    e0 = e0 + w011 * g.t3.x; e1 = e1 + w011 * g.t3.y;
    e0 = e0 + w100 * g.t4.x; e1 = e1 + w100 * g.t4.y;
    e0 = e0 + w101 * g.t5.x; e1 = e1 + w101 * g.t5.y;
    e0 = e0 + w110 * g.t6.x; e1 = e1 + w110 * g.t6.y;
    e0 = e0 + w111 * g.t7.x; e1 = e1 + w111 * g.t7.y;
    Enc2 r; r.e0 = e0; r.e1 = e1; return r;
}

// enc pair + backward coeffs (coeffs value-continuous: fmaf ok)
__device__ __forceinline__ EncA lv_enc_a(const Gather g)
{
#pragma clang fp contract(off)
    const float gx0 = 1.0f - g.fx, gx1 = g.fx;
    const float gy0 = 1.0f - g.fy, gy1 = g.fy;
    const float gz0 = 1.0f - g.fz, gz1 = g.fz;
    const float pxy00 = gx0 * gy0, pxy01 = gx0 * gy1, pxy10 = gx1 * gy0, pxy11 = gx1 * gy1;
    const float w000 = pxy00 * gz0, w001 = pxy00 * gz1, w010 = pxy01 * gz0, w011 = pxy01 * gz1;
    const float w100 = pxy10 * gz0, w101 = pxy10 * gz1, w110 = pxy11 * gz0, w111 = pxy11 * gz1;
    float e0 = 0.0f, e1 = 0.0f;
    e0 = e0 + w000 * g.t0.x; e1 = e1 + w000 * g.t0.y;
    e0 = e0 + w001 * g.t1.x; e1 = e1 + w001 * g.t1.y;
    e0 = e0 + w010 * g.t2.x; e1 = e1 + w010 * g.t2.y;
    e0 = e0 + w011 * g.t3.x; e1 = e1 + w011 * g.t3.y;
    e0 = e0 + w100 * g.t4.x; e1 = e1 + w100 * g.t4.y;
    e0 = e0 + w101 * g.t5.x; e1 = e1 + w101 * g.t5.y;
    e0 = e0 + w110 * g.t6.x; e1 = e1 + w110 * g.t6.y;
    e0 = e0 + w111 * g.t7.x; e1 = e1 + w111 * g.t7.y;
    const float pyz00 = gy0 * gz0, pyz01 = gy0 * gz1, pyz10 = gy1 * gz0, pyz11 = gy1 * gz1;
    const float pxz00 = gx0 * gz0, pxz01 = gx0 * gz1, pxz10 = gx1 * gz0, pxz11 = gx1 * gz1;
    float a0x = 0.f, a0y = 0.f, a0z = 0.f, a1x = 0.f, a1y = 0.f, a1z = 0.f;
    a0x = fmaf(-pyz00, g.t0.x, a0x); a1x = fmaf(-pyz00, g.t0.y, a1x);
    a0y = fmaf(-pxz00, g.t0.x, a0y); a1y = fmaf(-pxz00, g.t0.y, a1y);
    a0z = fmaf(-pxy00, g.t0.x, a0z); a1z = fmaf(-pxy00, g.t0.y, a1z);
    a0x = fmaf(-pyz01, g.t1.x, a0x); a1x = fmaf(-pyz01, g.t1.y, a1x);
    a0y = fmaf(-pxz01, g.t1.x, a0y); a1y = fmaf(-pxz01, g.t1.y, a1y);
    a0z = fmaf( pxy00, g.t1.x, a0z); a1z = fmaf( pxy00, g.t1.y, a1z);
    a0x = fmaf(-pyz10, g.t2.x, a0x); a1x = fmaf(-pyz10, g.t2.y, a1x);
    a0y = fmaf( pxz00, g.t2.x, a0y); a1y = fmaf( pxz00, g.t2.y, a1y);
    a0z = fmaf(-pxy01, g.t2.x, a0z); a1z = fmaf(-pxy01, g.t2.y, a1z);
    a0x = fmaf(-pyz11, g.t3.x, a0x); a1x = fmaf(-pyz11, g.t3.y, a1x);
    a0y = fmaf( pxz01, g.t3.x, a0y); a1y = fmaf( pxz01, g.t3.y, a1y);
    a0z = fmaf( pxy01, g.t3.x, a0z); a1z = fmaf( pxy01, g.t3.y, a1z);
    a0x = fmaf( pyz00, g.t4.x, a0x); a1x = fmaf( pyz00, g.t4.y, a1x);
    a0y = fmaf(-pxz10, g.t4.x, a0y); a1y = fmaf(-pxz10, g.t4.y, a1y);
    a0z = fmaf(-pxy10, g.t4.x, a0z); a1z = fmaf(-pxy10, g.t4.y, a1z);
    a0x = fmaf( pyz01, g.t5.x, a0x); a1x = fmaf( pyz01, g.t5.y, a1x);
    a0y = fmaf(-pxz11, g.t5.x, a0y); a1y = fmaf(-pxz11, g.t5.y, a1y);
    a0z = fmaf( pxy10, g.t5.x, a0z); a1z = fmaf( pxy10, g.t5.y, a1z);
    a0x = fmaf( pyz10, g.t6.x, a0x); a1x = fmaf( pyz10, g.t6.y, a1x);
    a0y = fmaf( pxz10, g.t6.x, a0y); a1y = fmaf( pxz10, g.t6.y, a1y);
    a0z = fmaf(-pxy11, g.t6.x, a0z); a1z = fmaf(-pxy11, g.t6.y, a1z);
    a0x = fmaf( pyz11, g.t7.x, a0x); a1x = fmaf( pyz11, g.t7.y, a1x);
    a0y = fmaf( pxz11, g.t7.x, a0y); a1y = fmaf( pxz11, g.t7.y, a1y);
    a0z = fmaf( pxy11, g.t7.x, a0z); a1z = fmaf( pxy11, g.t7.y, a1z);
    EncA r;
    r.e0 = e0; r.e1 = e1;
    r.a0x = a0x; r.a0y = a0y; r.a0z = a0z;
    r.a1x = a1x; r.a1y = a1y; r.a1z = a1z;
    return r;
}

// backward partial for re-gathered dense levels (fmaf ok)
__device__ __forceinline__ L3v bwd_part(const Gather g, const float g0, const float g1)
{
    const float gx0 = 1.0f - g.fx, gx1 = g.fx;
    const float gy0 = 1.0f - g.fy, gy1 = g.fy;
    const float gz0 = 1.0f - g.fz, gz1 = g.fz;
    const float pyz00 = gy0 * gz0, pyz01 = gy0 * gz1, pyz10 = gy1 * gz0, pyz11 = gy1 * gz1;
    const float pxz00 = gx0 * gz0, pxz01 = gx0 * gz1, pxz10 = gx1 * gz0, pxz11 = gx1 * gz1;
    const float pxy00 = gx0 * gy0, pxy01 = gx0 * gy1, pxy10 = gx1 * gy0, pxy11 = gx1 * gy1;
    const float s000 = fmaf(g0, g.t0.x, g1 * g.t0.y);
    const float s001 = fmaf(g0, g.t1.x, g1 * g.t1.y);
    const float s010 = fmaf(g0, g.t2.x, g1 * g.t2.y);
    const float s011 = fmaf(g0, g.t3.x, g1 * g.t3.y);
    const float s100 = fmaf(g0, g.t4.x, g1 * g.t4.y);
    const float s101 = fmaf(g0, g.t5.x, g1 * g.t5.y);
    const float s110 = fmaf(g0, g.t6.x, g1 * g.t6.y);
    const float s111 = fmaf(g0, g.t7.x, g1 * g.t7.y);
    float lx = 0.f, ly = 0.f, lz = 0.f;
    lx = fmaf(-pyz00, s000, lx); ly = fmaf(-pxz00, s000, ly); lz = fmaf(-pxy00, s000, lz);
    lx = fmaf(-pyz01, s001, lx); ly = fmaf(-pxz01, s001, ly); lz = fmaf( pxy00, s001, lz);
    lx = fmaf(-pyz10, s010, lx); ly = fmaf( pxz00, s010, ly); lz = fmaf(-pxy01, s010, lz);
    lx = fmaf(-pyz11, s011, lx); ly = fmaf( pxz01, s011, ly); lz = fmaf( pxy01, s011, lz);
    lx = fmaf( pyz00, s100, lx); ly = fmaf(-pxz10, s100, ly); lz = fmaf(-pxy10, s100, lz);
    lx = fmaf( pyz01, s101, lx); ly = fmaf(-pxz11, s101, ly); lz = fmaf( pxy10, s101, lz);
    lx = fmaf( pyz10, s110, lx); ly = fmaf( pxz10, s110, ly); lz = fmaf(-pxy11, s110, lz);
    lx = fmaf( pyz11, s111, lx); ly = fmaf( pxz11, s111, ly); lz = fmaf( pxy11, s111, lz);
    L3v r; r.lx = lx; r.ly = ly; r.lz = lz; return r;
}

__device__ __forceinline__ void clampedxn(const float* __restrict__ x, const int n,
                                          float& xn0, float& xn1, float& xn2)
{
    const float x0 = x[(size_t)n * 6 + 0];
    const float x1 = x[(size_t)n * 6 + 1];
    const float x2 = x[(size_t)n * 6 + 2];
    xn0 = fminf(fmaxf((x0 + 1.0f) * 0.5f, 0.0f), 1.0f);
    xn1 = fminf(fmaxf((x1 + 1.0f) * 0.5f, 0.0f), 1.0f);
    xn2 = fminf(fmaxf((x2 + 1.0f) * 0.5f, 0.0f), 1.0f);
}

// ============================================================================
// K1: level-phased gather — R11 form (16 phases, one level each; one level's
// 4MB table == one XCD L2). Measured: 306us, FETCH 483MB.
// ============================================================================
__global__ __launch_bounds__(256) __attribute__((amdgpu_waves_per_eu(8, 8)))
void k_gather_phased(const float* __restrict__ x, const float* __restrict__ tables,
                     float* __restrict__ ws, Params P)
{
    const int lvl = blockIdx.x >> 11;                      // 2048 blocks/level
    const int n = ((blockIdx.x & 2047) << 8) + threadIdx.x;
    if (n >= N_POINTS) return;
    const size_t N = (size_t)N_POINTS;
    float xn0, xn1, xn2;
    clampedxn(x, n, xn0, xn1, xn2);
    const float2* __restrict__ tb = (const float2*)tables;
    float* __restrict__ we = ws;               // [32][N] enc
    float* __restrict__ wa = ws + 32 * N;      // [66][N] A coeffs (c*NA + i)

    const int res = P.res[lvl];
    const bool hashed = (long long)res * res * res > (long long)TSZ;
    const Gather g = lv_issue_rt(tb + (size_t)lvl * TSZ, res, hashed, xn0, xn1, xn2);

    if (lvl >= ASTART) {
        const EncA r = lv_enc_a(g);
        we[(size_t)(2 * lvl) * N + n] = r.e0;
        we[(size_t)(2 * lvl + 1) * N + n] = r.e1;
        const int i_ = lvl - ASTART;
        wa[(size_t)(0 * NA + i_) * N + n] = r.a0x;
        wa[(size_t)(1 * NA + i_) * N + n] = r.a0y;
        wa[(size_t)(2 * NA + i_) * N + n] = r.a0z;
        wa[(size_t)(3 * NA + i_) * N + n] = r.a1x;
        wa[(size_t)(4 * NA + i_) * N + n] = r.a1y;
        wa[(size_t)(5 * NA + i_) * N + n] = r.a1z;
    } else {
        const Enc2 r = lv_enc(g);
        we[(size_t)(2 * lvl) * N + n] = r.e0;
        we[(size_t)(2 * lvl + 1) * N + n] = r.e1;
    }
}

// ============================================================================
// K2a: density MLP + genc (FUSED k-loop, one ws0 traversal, order-preserving)
// + backward gradient + true normal. ws0/ws1 staged in LDS (12KB): strided
// s_loads (~250cy each iteration) -> back-to-back LDS broadcasts (~60cy).
// ============================================================================
__global__ __launch_bounds__(256) __attribute__((amdgpu_waves_per_eu(4, 4)))
void k_density(const float* __restrict__ x, const float* __restrict__ tables,
               const float* __restrict__ w_s0, const float* __restrict__ w_s1,
               const float* __restrict__ ws, float* __restrict__ wgeo,
               float* __restrict__ out, Params P)
{
    __shared__ float w0L[32 * 64];   // 8KB
    __shared__ float w1L[64 * 16];   // 4KB
    for (int i = threadIdx.x; i < 32 * 64; i += 256) w0L[i] = w_s0[i];
    for (int i = threadIdx.x; i < 64 * 16; i += 256) w1L[i] = w_s1[i];
    __syncthreads();

    const int n = blockIdx.x * 256 + threadIdx.x;
    if (n >= N_POINTS) return;
    const size_t N = (size_t)N_POINTS;
    float xn0, xn1, xn2;
    clampedxn(x, n, xn0, xn1, xn2);
    const float2* __restrict__ tb = (const float2*)tables;
    const float* __restrict__ we = ws;
    const float* __restrict__ wa = ws + 32 * N;

    float enc[32];
    #pragma unroll
    for (int j = 0; j < 32; ++j) enc[j] = we[(size_t)j * N + n];

    // ---- density MLP + genc fused: same k order, same mul/add order as the
    //      two-loop form -> bit-identical results. ----
    float hd[16];
    #pragma unroll
    for (int m = 0; m < 16; ++m) hd[m] = 0.0f;
    float genc[32];
    #pragma unroll
    for (int j = 0; j < 32; ++j) genc[j] = 0.0f;
    {
        #pragma clang fp contract(off)
        for (int k = 0; k < 64; ++k) {
            float a = 0.0f;
            #pragma unroll
            for (int j = 0; j < 32; ++j) {
                const float p = enc[j] * w0L[j * 64 + k];
                a = a + p;
            }
            const float hr = fmaxf(a, 0.0f);
            #pragma unroll
            for (int m = 0; m < 16; ++m) hd[m] = fmaf(hr, w1L[k * 16 + m], hd[m]);
            const float ghk = (a > 0.0f) ? w1L[k * 16] : 0.0f;
            #pragma unroll
            for (int j = 0; j < 32; ++j) genc[j] = fmaf(w0L[j * 64 + k], ghk, genc[j]);
        }
    }

    // ---- write sigma + geo (frees hd pressure for backward phase) ----
    out[n] = hd[0];
    #pragma unroll
    for (int j = 0; j < 15; ++j) {
        out[N + (size_t)n * 15 + j] = hd[1 + j];
        wgeo[(size_t)j * N + n] = hd[1 + j];
    }

    // ---- backward: dense levels in 2-level pairs (L2-hot tiny tables) ----
    float gx = 0.0f, gy = 0.0f, gz = 0.0f;
    {
        const Gather gA = lv_issue<false>(tb + 0 * (size_t)TSZ, P.res[0], xn0, xn1, xn2);
        const Gather gB = lv_issue<false>(tb + 1 * (size_t)TSZ, P.res[1], xn0, xn1, xn2);
        {
            const L3v d = bwd_part(gA, genc[0], genc[1]);
            const float rf = (float)(P.res[0] - 1);
            gx = fmaf(d.lx, rf, gx); gy = fmaf(d.ly, rf, gy); gz = fmaf(d.lz, rf, gz);
        }
        {
            const L3v d = bwd_part(gB, genc[2], genc[3]);
            const float rf = (float)(P.res[1] - 1);
            gx = fmaf(d.lx, rf, gx); gy = fmaf(d.ly, rf, gy); gz = fmaf(d.lz, rf, gz);
        }
    }
    {
        const Gather gA = lv_issue<false>(tb + 2 * (size_t)TSZ, P.res[2], xn0, xn1, xn2);
        const Gather gB = lv_issue<false>(tb + 3 * (size_t)TSZ, P.res[3], xn0, xn1, xn2);
        {
            const L3v d = bwd_part(gA, genc[4], genc[5]);
            const float rf = (float)(P.res[2] - 1);
            gx = fmaf(d.lx, rf, gx); gy = fmaf(d.ly, rf, gy); gz = fmaf(d.lz, rf, gz);
        }
        {
            const L3v d = bwd_part(gB, genc[6], genc[7]);
            const float rf = (float)(P.res[3] - 1);
            gx = fmaf(d.lx, rf, gx); gy = fmaf(d.ly, rf, gy); gz = fmaf(d.lz, rf, gz);
        }
    }
    {
        const Gather gA = lv_issue<false>(tb + 4 * (size_t)TSZ, P.res[4], xn0, xn1, xn2);
        const L3v d = bwd_part(gA, genc[8], genc[9]);
        const float rf = (float)(P.res[4] - 1);
        gx = fmaf(d.lx, rf, gx); gy = fmaf(d.ly, rf, gy); gz = fmaf(d.lz, rf, gz);
    }

    // ---- high levels: stream A from ws (coalesced; static i via unroll) ----
    #pragma unroll
    for (int l = ASTART; l < NLV; ++l) {
        const int i = l - ASTART;
        const float rf = (float)(P.res[l] - 1);
        const float g0 = genc[2 * l], g1 = genc[2 * l + 1];
        const float a0x = wa[(size_t)(0*NA + i)*N + n];
        const float a0y = wa[(size_t)(1*NA + i)*N + n];
        const float a0z = wa[(size_t)(2*NA + i)*N + n];
        const float a1x = wa[(size_t)(3*NA + i)*N + n];
        const float a1y = wa[(size_t)(4*NA + i)*N + n];
        const float a1z = wa[(size_t)(5*NA + i)*N + n];
        gx = fmaf(rf, fmaf(g0, a0x, g1 * a1x), gx);
        gy = fmaf(rf, fmaf(g0, a0y, g1 * a1y), gy);
        gz = fmaf(rf, fmaf(g0, a0z, g1 * a1z), gz);
    }
    gx *= 0.5f; gy *= 0.5f; gz *= 0.5f;

    const float gnorm = sqrtf(gx * gx + gy * gy + gz * gz);
    const float ginv = 1.0f / fmaxf(gnorm, 1e-8f);

    out[16 * N + (size_t)n * 3 + 0] = -gx * ginv;
    out[16 * N + (size_t)n * 3 + 1] = -gy * ginv;
    out[16 * N + (size_t)n * 3 + 2] = -gz * ginv;
}

// ============================================================================
// K2b: pred_normal + mirror + color MLP. Strided weights (wc0, wn0, wm0)
// staged in LDS (13.7KB); wc1 rows contiguous -> stay global (dwordx16).
// ============================================================================
__global__ __launch_bounds__(256) __attribute__((amdgpu_waves_per_eu(4, 4)))
void k_color(const float* __restrict__ x,
             const float* __restrict__ wc0, const float* __restrict__ wc1,
             const float* __restrict__ wc2,
             const float* __restrict__ wn0, const float* __restrict__ wn1,
             const float* __restrict__ wm0, const float* __restrict__ bm0,
             const float* __restrict__ wm1, const float* __restrict__ bm1,
             const float* __restrict__ wgeo, float* __restrict__ out)
{
    __shared__ float c0L[31 * 64];   // 7.75KB
    __shared__ float n0L[15 * 64];   // 3.75KB
    __shared__ float m0L[15 * 32];   // 1.875KB
    for (int i = threadIdx.x; i < 31 * 64; i += 256) c0L[i] = wc0[i];
    for (int i = threadIdx.x; i < 15 * 64; i += 256) n0L[i] = wn0[i];
    for (int i = threadIdx.x; i < 15 * 32; i += 256) m0L[i] = wm0[i];
    __syncthreads();

    const int n = blockIdx.x * 256 + threadIdx.x;
    if (n >= N_POINTS) return;
    const size_t N = (size_t)N_POINTS;

    float geo[15];
    #pragma unroll
    for (int j = 0; j < 15; ++j) geo[j] = wgeo[(size_t)j * N + n];

    // ---- pred_normal = l2_normalize(relu(geo @ wn0) @ wn1) ----
    float pn0 = 0.0f, pn1 = 0.0f, pn2 = 0.0f;
    for (int k = 0; k < 64; ++k) {
        float a = 0.0f;
        #pragma unroll
        for (int j = 0; j < 15; ++j) a = fmaf(geo[j], n0L[j * 64 + k], a);
        a = fmaxf(a, 0.0f);
        pn0 = fmaf(a, wn1[k * 3 + 0], pn0);
        pn1 = fmaf(a, wn1[k * 3 + 1], pn1);
        pn2 = fmaf(a, wn1[k * 3 + 2], pn2);
    }
    const float pnorm = sqrtf(pn0 * pn0 + pn1 * pn1 + pn2 * pn2);
    const float pinv = 1.0f / fmaxf(pnorm, 1e-8f);
    out[19 * N + (size_t)n * 3 + 0] = pn0 * pinv;
    out[19 * N + (size_t)n * 3 + 1] = pn1 * pinv;
    out[19 * N + (size_t)n * 3 + 2] = pn2 * pinv;

    // ---- mirror head ----
    float macc = 0.0f;
    for (int k = 0; k < 32; ++k) {
        float a = bm0[k];
        #pragma unroll
        for (int j = 0; j < 15; ++j) a = fmaf(geo[j], m0L[j * 32 + k], a);
        a = (a >= 0.0f) ? a : 0.01f * a;
        macc = fmaf(a, wm1[k], macc);
    }
    macc += bm1[0];
    out[25 * N + n] = 1.0f / (1.0f + expf(-macc));

    // ---- spherical harmonics of d ----
    const float dx = x[(size_t)n * 6 + 3];
    const float dy = x[(size_t)n * 6 + 4];
    const float dz = x[(size_t)n * 6 + 5];
    float sh[16];
    const float xy = dx * dy, xz = dx * dz, yz = dy * dz;
    const float x2s = dx * dx, y2s = dy * dy, z2s = dz * dz;
    sh[0]  = 0.28209479177387814f;
    sh[1]  = -0.48860251190291987f * dy;
    sh[2]  =  0.48860251190291987f * dz;
    sh[3]  = -0.48860251190291987f * dx;
    sh[4]  =  1.0925484305920792f * xy;
    sh[5]  = -1.0925484305920792f * yz;
    sh[6]  =  0.94617469575756f * z2s - 0.31539156525252005f;
    sh[7]  = -1.0925484305920792f * xz;
    sh[8]  =  0.5462742152960396f * (x2s - y2s);
    sh[9]  =  0.5900435899266435f * dy * (-3.0f * x2s + y2s);
    sh[10] =  2.890611442640554f * xy * dz;
    sh[11] =  0.4570457994644657f * dy * (1.0f - 5.0f * z2s);
    sh[12] =  0.3731763325901154f * dz * (5.0f * z2s - 3.0f);
    sh[13] =  0.4570457994644657f * dx * (1.0f - 5.0f * z2s);
    sh[14] =  1.445305721320277f * dz * (x2s - y2s);
    sh[15] =  0.5900435899266435f * dx * (x2s - 3.0f * y2s);

    // ---- color MLP: [sh, geo] (31) -> 64 -> 64 -> 3, sigmoid ----
    float cacc[64];
    #pragma unroll
    for (int k = 0; k < 64; ++k) cacc[k] = 0.0f;
    for (int kc = 0; kc < 64; ++kc) {
        float a = 0.0f;
        #pragma unroll
        for (int j = 0; j < 16; ++j) a = fmaf(sh[j], c0L[j * 64 + kc], a);
        #pragma unroll
        for (int j = 0; j < 15; ++j) a = fmaf(geo[j], c0L[(16 + j) * 64 + kc], a);
        const float c1v = fmaxf(a, 0.0f);
        const float* __restrict__ wrow = wc1 + kc * 64;
        #pragma unroll
        for (int k2 = 0; k2 < 64; ++k2) cacc[k2] = fmaf(c1v, wrow[k2], cacc[k2]);
    }
    float r0 = 0.0f, r1 = 0.0f, r2 = 0.0f;
    #pragma unroll
    for (int k = 0; k < 64; ++k) {
        const float a = fmaxf(cacc[k], 0.0f);
        r0 = fmaf(a, wc2[k * 3 + 0], r0);
        r1 = fmaf(a, wc2[k * 3 + 1], r1);
        r2 = fmaf(a, wc2[k * 3 + 2], r2);
    }
    out[22 * N + (size_t)n * 3 + 0] = 1.0f / (1.0f + expf(-r0));
    out[22 * N + (size_t)n * 3 + 1] = 1.0f / (1.0f + expf(-r1));
    out[22 * N + (size_t)n * 3 + 2] = 1.0f / (1.0f + expf(-r2));
}

// ============================================================================
// Fallback: R5 mono kernel (verified passing) — used if ws too small.
// ============================================================================
__global__ __launch_bounds__(256) __attribute__((amdgpu_waves_per_eu(3, 4)))
void nerf_mono(const float* __restrict__ x, const float* __restrict__ tables,
               const float* __restrict__ w_s0, const float* __restrict__ w_s1,
               const float* __restrict__ wc0, const float* __restrict__ wc1,
               const float* __restrict__ wc2, const float* __restrict__ wn0,
               const float* __restrict__ wn1, const float* __restrict__ wm0,
               const float* __restrict__ bm0, const float* __restrict__ wm1,
               const float* __restrict__ bm1, float* __restrict__ out, Params P)
{
    const int n = blockIdx.x * 256 + threadIdx.x;
    if (n >= N_POINTS) return;
    float xn0, xn1, xn2;
    clampedxn(x, n, xn0, xn1, xn2);
    const float2* __restrict__ tb = (const float2*)tables;

    float enc[32];
    float A0x[NA], A0y[NA], A0z[NA], A1x[NA], A1y[NA], A1z[NA];

#define MPAIR_NN(LA, LB) {                                                             \
        const Gather gA = lv_issue<false>(tb + (size_t)(LA)*TSZ, P.res[LA], xn0, xn1, xn2); \
        const Gather gB = lv_issue<false>(tb + (size_t)(LB)*TSZ, P.res[LB], xn0, xn1, xn2); \
        const Enc2 rA = lv_enc(gA); enc[2*(LA)] = rA.e0; enc[2*(LA)+1] = rA.e1;        \
        const Enc2 rB = lv_enc(gB); enc[2*(LB)] = rB.e0; enc[2*(LB)+1] = rB.e1; }
#define MPAIR_NA(LA, LB) {                                                             \
        const Gather gA = lv_issue<false>(tb + (size_t)(LA)*TSZ, P.res[LA], xn0, xn1, xn2); \
        const Gather gB = lv_issue<false>(tb + (size_t)(LB)*TSZ, P.res[LB], xn0, xn1, xn2); \
        const Enc2 rA = lv_enc(gA); enc[2*(LA)] = rA.e0; enc[2*(LA)+1] = rA.e1;        \
        const EncA rB = lv_enc_a(gB); enc[2*(LB)] = rB.e0; enc[2*(LB)+1] = rB.e1;      \
        A0x[(LB)-ASTART] = rB.a0x; A0y[(LB)-ASTART] = rB.a0y; A0z[(LB)-ASTART] = rB.a0z; \
        A1x[(LB)-ASTART] = rB.a1x; A1y[(LB)-ASTART] = rB.a1y; A1z[(LB)-ASTART] = rB.a1z; }
#define MPAIR_AA(LA, LB) {                                                             \
        const Gather gA = lv_issue<true>(tb + (size_t)(LA)*TSZ, P.res[LA], xn0, xn1, xn2);  \
        const Gather gB = lv_issue<true>(tb + (size_t)(LB)*TSZ, P.res[LB], xn0, xn1, xn2);  \
        const EncA rA = lv_enc_a(gA); enc[2*(LA)] = rA.e0; enc[2*(LA)+1] = rA.e1;      \
        A0x[(LA)-ASTART] = rA.a0x; A0y[(LA)-ASTART] = rA.a0y; A0z[(LA)-ASTART] = rA.a0z; \
        A1x[(LA)-ASTART] = rA.a1x; A1y[(LA)-ASTART] = rA.a1y; A1z[(LA)-ASTART] = rA.a1z; \
        const EncA rB = lv_enc_a(gB); enc[2*(LB)] = rB.e0; enc[2*(LB)+1] = rB.e1;      \
        A0x[(LB)-ASTART] = rB.a0x; A0y[(LB)-ASTART] = rB.a0y; A0z[(LB)-ASTART] = rB.a0z; \
        A1x[(LB)-ASTART] = rB.a1x; A1y[(LB)-ASTART] = rB.a1y; A1z[(LB)-ASTART] = rB.a1z; }

    MPAIR_NN(0, 1)
    MPAIR_NN(2, 3)
    MPAIR_NA(4, 5)
    MPAIR_AA(6, 7)
    MPAIR_AA(8, 9)
    MPAIR_AA(10, 11)
    MPAIR_AA(12, 13)
    MPAIR_AA(14, 15)
#undef MPAIR_NN
#undef MPAIR_NA
#undef MPAIR_AA

    float hd[16];
    #pragma unroll
    for (int m = 0; m < 16; ++m) hd[m] = 0.0f;
    unsigned long long mask = 0ull;
    {
        #pragma clang fp contract(off)
        for (int k = 0; k < 64; ++k) {
            float a = 0.0f;
            #pragma unroll
            for (int j = 0; j < 32; ++j) {
                const float p = enc[j] * w_s0[j * 64 + k];
                a = a + p;
            }
            const float hr = fmaxf(a, 0.0f);
            #pragma unroll
            for (int m = 0; m < 16; ++m) hd[m] = fmaf(hr, w_s1[k * 16 + m], hd[m]);
            if (a > 0.0f) mask |= (1ull << k);
        }
    }
    const float sigma = hd[0];

    float gx = 0.0f, gy = 0.0f, gz = 0.0f;
    {
        const Gather g0v = lv_issue<false>(tb + 0 * (size_t)TSZ, P.res[0], xn0, xn1, xn2);
        const Gather g1v = lv_issue<false>(tb + 1 * (size_t)TSZ, P.res[1], xn0, xn1, xn2);

        float genc[32];
        #pragma unroll
        for (int j = 0; j < 32; ++j) genc[j] = 0.0f;
        for (int k = 0; k < 64; ++k) {
            const float ghk = ((mask >> k) & 1ull) ? w_s1[k * 16] : 0.0f;
            #pragma unroll
            for (int j = 0; j < 32; ++j) genc[j] = fmaf(w_s0[j * 64 + k], ghk, genc[j]);
        }

        {
            const L3v d = bwd_part(g0v, genc[0], genc[1]);
            const float rf = (float)(P.res[0] - 1);
            gx = fmaf(d.lx, rf, gx); gy = fmaf(d.ly, rf, gy); gz = fmaf(d.lz, rf, gz);
        }
        {
            const L3v d = bwd_part(g1v, genc[2], genc[3]);
            const float rf = (float)(P.res[1] - 1);
            gx = fmaf(d.lx, rf, gx); gy = fmaf(d.ly, rf, gy); gz = fmaf(d.lz, rf, gz);
        }
        {
            const Gather g2v = lv_issue<false>(tb + 2 * (size_t)TSZ, P.res[2], xn0, xn1, xn2);
            const Gather g3v = lv_issue<false>(tb + 3 * (size_t)TSZ, P.res[3], xn0, xn1, xn2);
            {
                const L3v d = bwd_part(g2v, genc[4], genc[5]);
                const float rf = (float)(P.res[2] - 1);
                gx = fmaf(d.lx, rf, gx); gy = fmaf(d.ly, rf, gy); gz = fmaf(d.lz, rf, gz);
            }
            {
                const L3v d = bwd_part(g3v, genc[6], genc[7]);
                const float rf = (float)(P.res[3] - 1);
                gx = fmaf(d.lx, rf, gx); gy = fmaf(d.ly, rf, gy); gz = fmaf(d.lz, rf, gz);
            }
        }
        {
            const Gather g4v = lv_issue<false>(tb + 4 * (size_t)TSZ, P.res[4], xn0, xn1, xn2);
            const L3v d = bwd_part(g4v, genc[8], genc[9]);
            const float rf = (float)(P.res[4] - 1);
            gx = fmaf(d.lx, rf, gx); gy = fmaf(d.ly, rf, gy); gz = fmaf(d.lz, rf, gz);
        }

        #pragma unroll
        for (int l = ASTART; l < NLV; ++l) {
            const int i = l - ASTART;
            const float rf = (float)(P.res[l] - 1);
            const float g0 = genc[2 * l], g1 = genc[2 * l + 1];
            gx = fmaf(rf, fmaf(g0, A0x[i], g1 * A1x[i]), gx);
            gy = fmaf(rf, fmaf(g0, A0y[i], g1 * A1y[i]), gy);
            gz = fmaf(rf, fmaf(g0, A0z[i], g1 * A1z[i]), gz);
        }
    }
    gx *= 0.5f; gy *= 0.5f; gz *= 0.5f;

    const float gnorm = sqrtf(gx * gx + gy * gy + gz * gz);
    const float ginv = 1.0f / fmaxf(gnorm, 1e-8f);

    float geo[15];
    #pragma unroll
    for (int j = 0; j < 15; ++j) geo[j] = hd[1 + j];

    float pn0 = 0.0f, pn1 = 0.0f, pn2 = 0.0f;
    for (int k = 0; k < 64; ++k) {
        float a = 0.0f;
        #pragma unroll
        for (int j = 0; j < 15; ++j) a = fmaf(geo[j], wn0[j * 64 + k], a);
        a = fmaxf(a, 0.0f);
        pn0 = fmaf(a, wn1[k * 3 + 0], pn0);
        pn1 = fmaf(a, wn1[k * 3 + 1], pn1);
        pn2 = fmaf(a, wn1[k * 3 + 2], pn2);
    }
    const float pnorm = sqrtf(pn0 * pn0 + pn1 * pn1 + pn2 * pn2);
    const float pinv = 1.0f / fmaxf(pnorm, 1e-8f);

    const float dx = x[(size_t)n * 6 + 3];
    const float dy = x[(size_t)n * 6 + 4];
    const float dz = x[(size_t)n * 6 + 5];
    float sh[16];
    const float xy = dx * dy, xz = dx * dz, yz = dy * dz;
    const float x2s = dx * dx, y2s = dy * dy, z2s = dz * dz;
    sh[0]  = 0.28209479177387814f;
    sh[1]  = -0.48860251190291987f * dy;
    sh[2]  =  0.48860251190291987f * dz;
    sh[3]  = -0.48860251190291987f * dx;
    sh[4]  =  1.0925484305920792f * xy;
    sh[5]  = -1.0925484305920792f * yz;
    sh[6]  =  0.94617469575756f * z2s - 0.31539156525252005f;
    sh[7]  = -1.0925484305920792f * xz;
    sh[8]  =  0.5462742152960396f * (x2s - y2s);
    sh[9]  =  0.5900435899266435f * dy * (-3.0f * x2s + y2s);
    sh[10] =  2.890611442640554f * xy * dz;
    sh[11] =  0.4570457994644657f * dy * (1.0f - 5.0f * z2s);
    sh[12] =  0.3731763325901154f * dz * (5.0f * z2s - 3.0f);
    sh[13] =  0.4570457994644657f * dx * (1.0f - 5.0f * z2s);
    sh[14] =  1.445305721320277f * dz * (x2s - y2s);
    sh[15] =  0.5900435899266435f * dx * (x2s - 3.0f * y2s);

    float cacc[64];
    #pragma unroll
    for (int k = 0; k < 64; ++k) cacc[k] = 0.0f;
    for (int kc = 0; kc < 64; ++kc) {
        float a = 0.0f;
        #pragma unroll
        for (int j = 0; j < 16; ++j) a = fmaf(sh[j], wc0[j * 64 + kc], a);
        #pragma unroll
        for (int j = 0; j < 15; ++j) a = fmaf(geo[j], wc0[(16 + j) * 64 + kc], a);
        const float c1v = fmaxf(a, 0.0f);
        const float* __restrict__ wrow = wc1 + kc * 64;
        #pragma unroll
        for (int k2 = 0; k2 < 64; ++k2) cacc[k2] = fmaf(c1v, wrow[k2], cacc[k2]);
    }
    float r0 = 0.0f, r1 = 0.0f, r2 = 0.0f;
    #pragma unroll
    for (int k = 0; k < 64; ++k) {
        const float a = fmaxf(cacc[k], 0.0f);
        r0 = fmaf(a, wc2[k * 3 + 0], r0);
        r1 = fmaf(a, wc2[k * 3 + 1], r1);
        r2 = fmaf(a, wc2[k * 3 + 2], r2);
    }
    const float rgb0 = 1.0f / (1.0f + expf(-r0));
    const float rgb1 = 1.0f / (1.0f + expf(-r1));
    const float rgb2 = 1.0f / (1.0f + expf(-r2));

    float macc = 0.0f;
    for (int k = 0; k < 32; ++k) {
        float a = bm0[k];
        #pragma unroll
        for (int j = 0; j < 15; ++j) a = fmaf(geo[j], wm0[j * 32 + k], a);
        a = (a >= 0.0f) ? a : 0.01f * a;
        macc = fmaf(a, wm1[k], macc);
    }
    macc += bm1[0];
    const float mir = 1.0f / (1.0f + expf(-macc));

    const size_t N = (size_t)N_POINTS;
    out[n] = sigma;
    #pragma unroll
    for (int j = 0; j < 15; ++j)
        out[N + (size_t)n * 15 + j] = geo[j];
    out[16 * N + (size_t)n * 3 + 0] = -gx * ginv;
    out[16 * N + (size_t)n * 3 + 1] = -gy * ginv;
    out[16 * N + (size_t)n * 3 + 2] = -gz * ginv;
    out[19 * N + (size_t)n * 3 + 0] = pn0 * pinv;
    out[19 * N + (size_t)n * 3 + 1] = pn1 * pinv;
    out[19 * N + (size_t)n * 3 + 2] = pn2 * pinv;
    out[22 * N + (size_t)n * 3 + 0] = rgb0;
    out[22 * N + (size_t)n * 3 + 1] = rgb1;
    out[22 * N + (size_t)n * 3 + 2] = rgb2;
    out[25 * N + n] = mir;
}

extern "C" void kernel_launch(void* const* d_in, const int* in_sizes, int n_in,
                              void* d_out, int out_size, void* d_ws, size_t ws_size,
                              hipStream_t stream)
{
    // Replicate Python's RES computation bit-for-bit:
    // PLS = exp2(log2(2048.0*BOUND/N_LEVELS)/(N_LEVELS-1)); RES[l] = floor(16*PLS**l)
    Params P;
    const double PLS = exp2(log2(2048.0 * 1.0 / 16.0) / 15.0);
    for (int l = 0; l < NLV; ++l)
        P.res[l] = (int)floor(16.0 * pow(PLS, (double)l));

    const float* x      = (const float*)d_in[0];
    const float* tables = (const float*)d_in[1];
    const float* w_s0   = (const float*)d_in[2];
    const float* w_s1   = (const float*)d_in[3];
    const float* wc0    = (const float*)d_in[4];
    const float* wc1    = (const float*)d_in[5];
    const float* wc2    = (const float*)d_in[6];
    const float* wn0    = (const float*)d_in[7];
    const float* wn1    = (const float*)d_in[8];
    const float* wm0    = (const float*)d_in[9];
    const float* bm0    = (const float*)d_in[10];
    const float* wm1    = (const float*)d_in[11];
    const float* bm1    = (const float*)d_in[12];
    float* out = (float*)d_out;

    const size_t N = (size_t)N_POINTS;
    const size_t need = (size_t)(32 + 66 + 15) * N * sizeof(float);   // 237 MB

    if (d_ws != nullptr && ws_size >= need) {
        float* ws   = (float*)d_ws;             // [32][N] enc + [66][N] A
        float* wgeo = ws + (size_t)98 * N;      // [15][N] geo
        k_gather_phased<<<NLV * (N_POINTS / 256), 256, 0, stream>>>(x, tables, ws, P);
        k_density<<<N_POINTS / 256, 256, 0, stream>>>(x, tables, w_s0, w_s1,
                                                      ws, wgeo, out, P);
        k_color  <<<N_POINTS / 256, 256, 0, stream>>>(x, wc0, wc1, wc2,
                                                      wn0, wn1, wm0, bm0, wm1, bm1,
                                                      wgeo, out);
    } else {
        nerf_mono<<<N_POINTS / 256, 256, 0, stream>>>(x, tables, w_s0, w_s1,
                                                      wc0, wc1, wc2, wn0, wn1,
                                                      wm0, bm0, wm1, bm1, out, P);
    }
}